// Round 7
// baseline (305.100 us; speedup 1.0000x reference)
//
#include <hip/hip_runtime.h>
#include <hip/hip_bf16.h>
#include <math.h>

#define NT 1200
#define NB 16384
#define NY 8
#define NGROUPS (NT * NB)                 // 19,660,800 channel-groups
#define NQ      (NT * NB * NY / 4)        // 39,321,600 float4 elements
#define GRID    768                       // exactly 3 blocks/CU on 256 CUs
#define BLOCK   256
#define NTHREADS (GRID * BLOCK)           // 196,608
#define CHUNK   8                         // 8 consecutive float4 = 128 B per array per iter
#define NITER   (NQ / (NTHREADS * CHUNK)) // 25, exact — no tail
#define W_LOW  0.2f
#define W_HIGH 1.75f

typedef float f32x4 __attribute__((ext_vector_type(4)));

// Stage 1: each thread reads 128 B CONTIGUOUS per array per iteration
// (8 consecutive dwordx4 -> 16 loads in flight, spatially adjacent).
// Chunk c covers float4s [8c..8c+7]: even float4 -> ch0-3, odd -> ch4-7
// (same mapping for every thread). 4096 chunks per timestep: t = c >> 12.
// Per-block partials -> ws[block*8+ch]; every slot overwritten every call,
// so no zero-init / no atomics needed.
__global__ __launch_bounds__(BLOCK) void rmse_partial_kernel(
    const float* __restrict__ outp, const float* __restrict__ tgtp,
    float* __restrict__ ws)
{
    const f32x4* __restrict__ o4 = reinterpret_cast<const f32x4*>(outp);
    const f32x4* __restrict__ t4 = reinterpret_cast<const f32x4*>(tgtp);

    const int c0 = blockIdx.x * BLOCK + threadIdx.x;

    f32x4 accA = {0.0f, 0.0f, 0.0f, 0.0f};   // channels 0-3
    f32x4 accB = {0.0f, 0.0f, 0.0f, 0.0f};   // channels 4-7

#pragma unroll 1
    for (int it = 0; it < NITER; ++it) {
        const int c   = c0 + it * NTHREADS;   // chunk index
        const int qb  = c << 3;               // first float4 of chunk
        const int t   = c >> 12;              // timestep (4096 chunks per t)
        const int mon = t % 12;
        const float w2 = (mon >= 6 && mon <= 9) ? (W_HIGH * W_HIGH)
                                                : (W_LOW * W_LOW);

        f32x4 a[CHUNK], b[CHUNK];
#pragma unroll
        for (int u = 0; u < CHUNK; ++u) a[u] = o4[qb + u];
#pragma unroll
        for (int u = 0; u < CHUNK; ++u) b[u] = t4[qb + u];

#pragma unroll
        for (int u = 0; u < CHUNK; u += 2) {
            f32x4 dA = a[u]     - b[u];
            f32x4 dB = a[u + 1] - b[u + 1];
            accA += (w2 * dA) * dA;
            accB += (w2 * dB) * dB;
        }
    }

    // Full 64-lane XOR butterfly — every thread has the same channel mapping.
#pragma unroll
    for (int mask = 1; mask <= 32; mask <<= 1) {
        accA.x += __shfl_xor(accA.x, mask, 64);
        accA.y += __shfl_xor(accA.y, mask, 64);
        accA.z += __shfl_xor(accA.z, mask, 64);
        accA.w += __shfl_xor(accA.w, mask, 64);
        accB.x += __shfl_xor(accB.x, mask, 64);
        accB.y += __shfl_xor(accB.y, mask, 64);
        accB.z += __shfl_xor(accB.z, mask, 64);
        accB.w += __shfl_xor(accB.w, mask, 64);
    }

    __shared__ float sh[4][NY];               // 4 waves per 256-thread block
    const int wave = threadIdx.x >> 6;
    const int lane = threadIdx.x & 63;
    if (lane == 0) {
        sh[wave][0] = accA.x; sh[wave][1] = accA.y;
        sh[wave][2] = accA.z; sh[wave][3] = accA.w;
        sh[wave][4] = accB.x; sh[wave][5] = accB.y;
        sh[wave][6] = accB.z; sh[wave][7] = accB.w;
    }
    __syncthreads();

    if (threadIdx.x < NY) {
        const int ch = threadIdx.x;
        ws[blockIdx.x * NY + ch] = sh[0][ch] + sh[1][ch] + sh[2][ch] + sh[3][ch];
    }
}

// Stage 2: reduce 768x8 block partials, then sum sqrt(mean) over channels.
__global__ __launch_bounds__(256) void rmse_final_kernel(
    const float* __restrict__ ws, float* __restrict__ out)
{
    // 256 threads: ch = tid & 7, slice = tid >> 3 (32 slices over 768 blocks).
    const int ch    = threadIdx.x & 7;
    const int slice = threadIdx.x >> 3;

    float s = 0.0f;
    for (int j = slice; j < GRID; j += 32)
        s += ws[j * NY + ch];

    // Lanes with the same ch within a wave are stride-8: reduce masks 8,16,32.
    s += __shfl_xor(s, 8, 64);
    s += __shfl_xor(s, 16, 64);
    s += __shfl_xor(s, 32, 64);
    // Now lanes 0..7 of each wave hold the per-wave channel sums.

    __shared__ float sh[4][NY];
    const int wave = threadIdx.x >> 6;
    const int lane = threadIdx.x & 63;
    if (lane < NY) sh[wave][lane] = s;
    __syncthreads();

    if (threadIdx.x == 0) {
        const float inv_n = 1.0f / (float)NGROUPS;  // mean over NT*NB per channel
        float total = 0.0f;
#pragma unroll
        for (int c = 0; c < NY; ++c) {
            float v = sh[0][c] + sh[1][c] + sh[2][c] + sh[3][c];
            total += sqrtf(v * inv_n);
        }
        out[0] = total;
    }
}

extern "C" void kernel_launch(void* const* d_in, const int* in_sizes, int n_in,
                              void* d_out, int out_size, void* d_ws, size_t ws_size,
                              hipStream_t stream) {
    const float* outp = (const float*)d_in[0];
    const float* tgtp = (const float*)d_in[1];
    float* ws  = (float*)d_ws;
    float* out = (float*)d_out;

    rmse_partial_kernel<<<GRID, BLOCK, 0, stream>>>(outp, tgtp, ws);
    rmse_final_kernel<<<1, 256, 0, stream>>>(ws, out);
}

// Round 8
// 232.990 us; speedup vs baseline: 1.3095x; 1.3095x over previous
//
#include <hip/hip_runtime.h>
#include <hip/hip_bf16.h>
#include <math.h>

#define NT 1200
#define NB 16384
#define NY 8
#define NGROUPS (NT * NB)                 // 19,660,800 channel-groups
#define NQ      (NT * NB * NY / 4)        // 39,321,600 float4 elements
#define NCHUNK  (NQ / 4)                  // 9,830,400 64B chunks
#define GRID    2048                      // 8 blocks/CU — 32 waves/CU (HW max)
#define BLOCK   256
#define NTHREADS (GRID * BLOCK)           // 524,288
#define NFULL   18                        // full iterations for all threads
#define NTAIL   (NCHUNK - NFULL * NTHREADS)  // 393,216 tail chunks
#define W_LOW  0.2f
#define W_HIGH 1.75f

typedef float f32x4 __attribute__((ext_vector_type(4)));

__device__ __forceinline__ void chunk_body(
    const f32x4* __restrict__ o4, const f32x4* __restrict__ t4,
    int c, f32x4& accA, f32x4& accB)
{
    const int qb  = c << 2;               // first float4 of chunk
    const int t   = c >> 13;              // timestep (8192 chunks per t)
    const int mon = t % 12;
    const float w2 = (mon >= 6 && mon <= 9) ? (W_HIGH * W_HIGH)
                                            : (W_LOW * W_LOW);

    f32x4 a0 = o4[qb + 0];
    f32x4 a1 = o4[qb + 1];
    f32x4 a2 = o4[qb + 2];
    f32x4 a3 = o4[qb + 3];
    f32x4 b0 = t4[qb + 0];
    f32x4 b1 = t4[qb + 1];
    f32x4 b2 = t4[qb + 2];
    f32x4 b3 = t4[qb + 3];

    f32x4 d0 = a0 - b0;
    f32x4 d1 = a1 - b1;
    f32x4 d2 = a2 - b2;
    f32x4 d3 = a3 - b3;

    accA += (w2 * d0) * d0;
    accB += (w2 * d1) * d1;
    accA += (w2 * d2) * d2;
    accB += (w2 * d3) * d3;
}

// Stage 1: 64 B contiguous per array per thread per iteration (R6 layout, best),
// at 32 waves/CU (launch_bounds caps VGPR at 64 for 8 blocks/CU residency).
// 18 uniform iterations + tail iteration for threads with c0 < NTAIL.
__global__ __launch_bounds__(BLOCK, 8) void rmse_partial_kernel(
    const float* __restrict__ outp, const float* __restrict__ tgtp,
    float* __restrict__ ws)
{
    const f32x4* __restrict__ o4 = reinterpret_cast<const f32x4*>(outp);
    const f32x4* __restrict__ t4 = reinterpret_cast<const f32x4*>(tgtp);

    const int c0 = blockIdx.x * BLOCK + threadIdx.x;

    f32x4 accA = {0.0f, 0.0f, 0.0f, 0.0f};   // channels 0-3
    f32x4 accB = {0.0f, 0.0f, 0.0f, 0.0f};   // channels 4-7

#pragma unroll 1
    for (int it = 0; it < NFULL; ++it)
        chunk_body(o4, t4, c0 + it * NTHREADS, accA, accB);

    if (c0 < NTAIL)
        chunk_body(o4, t4, c0 + NFULL * NTHREADS, accA, accB);

    // Full 64-lane XOR butterfly — every thread has the same channel mapping.
#pragma unroll
    for (int mask = 1; mask <= 32; mask <<= 1) {
        accA.x += __shfl_xor(accA.x, mask, 64);
        accA.y += __shfl_xor(accA.y, mask, 64);
        accA.z += __shfl_xor(accA.z, mask, 64);
        accA.w += __shfl_xor(accA.w, mask, 64);
        accB.x += __shfl_xor(accB.x, mask, 64);
        accB.y += __shfl_xor(accB.y, mask, 64);
        accB.z += __shfl_xor(accB.z, mask, 64);
        accB.w += __shfl_xor(accB.w, mask, 64);
    }

    __shared__ float sh[4][NY];               // 4 waves per 256-thread block
    const int wave = threadIdx.x >> 6;
    const int lane = threadIdx.x & 63;
    if (lane == 0) {
        sh[wave][0] = accA.x; sh[wave][1] = accA.y;
        sh[wave][2] = accA.z; sh[wave][3] = accA.w;
        sh[wave][4] = accB.x; sh[wave][5] = accB.y;
        sh[wave][6] = accB.z; sh[wave][7] = accB.w;
    }
    __syncthreads();

    if (threadIdx.x < NY) {
        const int ch = threadIdx.x;
        ws[blockIdx.x * NY + ch] = sh[0][ch] + sh[1][ch] + sh[2][ch] + sh[3][ch];
    }
}

// Stage 2: reduce GRID x 8 block partials, then sum sqrt(mean) over channels.
__global__ __launch_bounds__(256) void rmse_final_kernel(
    const float* __restrict__ ws, float* __restrict__ out)
{
    const int ch    = threadIdx.x & 7;        // channel
    const int slice = threadIdx.x >> 3;       // 32 slices over GRID blocks

    float s = 0.0f;
    for (int j = slice; j < GRID; j += 32)
        s += ws[j * NY + ch];

    // Same-channel lanes are stride-8 within the wave: masks 8,16,32.
    s += __shfl_xor(s, 8, 64);
    s += __shfl_xor(s, 16, 64);
    s += __shfl_xor(s, 32, 64);

    __shared__ float sh[4][NY];
    const int wave = threadIdx.x >> 6;
    const int lane = threadIdx.x & 63;
    if (lane < NY) sh[wave][lane] = s;
    __syncthreads();

    if (threadIdx.x == 0) {
        const float inv_n = 1.0f / (float)NGROUPS;  // mean over NT*NB per channel
        float total = 0.0f;
#pragma unroll
        for (int c = 0; c < NY; ++c) {
            float v = sh[0][c] + sh[1][c] + sh[2][c] + sh[3][c];
            total += sqrtf(v * inv_n);
        }
        out[0] = total;
    }
}

extern "C" void kernel_launch(void* const* d_in, const int* in_sizes, int n_in,
                              void* d_out, int out_size, void* d_ws, size_t ws_size,
                              hipStream_t stream) {
    const float* outp = (const float*)d_in[0];
    const float* tgtp = (const float*)d_in[1];
    float* ws  = (float*)d_ws;
    float* out = (float*)d_out;

    rmse_partial_kernel<<<GRID, BLOCK, 0, stream>>>(outp, tgtp, ws);
    rmse_final_kernel<<<1, 256, 0, stream>>>(ws, out);
}

// Round 9
// 223.266 us; speedup vs baseline: 1.3665x; 1.0436x over previous
//
#include <hip/hip_runtime.h>
#include <hip/hip_bf16.h>
#include <math.h>

#define NT 1200
#define NB 16384
#define NY 8
#define NGROUPS (NT * NB)                 // 19,660,800 channel-groups
#define NQ      (NT * NB * NY / 4)        // 39,321,600 float4 elements
#define GRID    1536                      // exactly 6 blocks/CU, 24 waves/CU (best measured)
#define BLOCK   256
#define NWAVES  (GRID * BLOCK / 64)       // 6144 waves
#define REGION  256                       // float4s per wave per iter = 4 KB
#define STRIPE  (NWAVES * REGION)         // 1,572,864 float4 per iteration
#define NITER   (NQ / STRIPE)             // 25, exact — no tail
#define W_LOW  0.2f
#define W_HIGH 1.75f

typedef float f32x4 __attribute__((ext_vector_type(4)));

// Stage 1: wave-chunked transpose layout. Each wave owns a contiguous 4 KB
// region per array per iteration; instruction u reads lane i at
// region + u*64 + i, so EVERY load instruction is perfectly coalesced
// (1 KiB contiguous) AND the wave's footprint is 4 KB contiguous —
// DRAM page locality without any cache-line overlap between instructions.
// q parity == lane parity (REGION, 64, STRIPE all even): even lanes
// accumulate ch0-3, odd lanes ch4-7.
// A 4 KB region spans 256 float4 within one timestep (32768 f4/t, aligned),
// so one seasonal weight per wave-iteration.
__global__ __launch_bounds__(BLOCK) void rmse_partial_kernel(
    const float* __restrict__ outp, const float* __restrict__ tgtp,
    float* __restrict__ ws)
{
    const f32x4* __restrict__ o4 = reinterpret_cast<const f32x4*>(outp);
    const f32x4* __restrict__ t4 = reinterpret_cast<const f32x4*>(tgtp);

    const int gwave = (blockIdx.x * BLOCK + threadIdx.x) >> 6;  // global wave id
    const int lane  = threadIdx.x & 63;
    const int rbase0 = gwave * REGION + lane;                   // lane's slot in region

    f32x4 acc = {0.0f, 0.0f, 0.0f, 0.0f};   // even lane: ch0-3, odd lane: ch4-7

#pragma unroll 1
    for (int it = 0; it < NITER; ++it) {
        const int qb = it * STRIPE + gwave * REGION;  // region base (uniform in wave)
        const int t  = qb >> 15;                      // 32768 float4 per timestep
        const int mon = t % 12;
        const float w2 = (mon >= 6 && mon <= 9) ? (W_HIGH * W_HIGH)
                                                : (W_LOW * W_LOW);

        const int q = it * STRIPE + rbase0;
        f32x4 a0 = o4[q];
        f32x4 a1 = o4[q + 64];
        f32x4 a2 = o4[q + 128];
        f32x4 a3 = o4[q + 192];
        f32x4 b0 = t4[q];
        f32x4 b1 = t4[q + 64];
        f32x4 b2 = t4[q + 128];
        f32x4 b3 = t4[q + 192];

        f32x4 d0 = a0 - b0;
        f32x4 d1 = a1 - b1;
        f32x4 d2 = a2 - b2;
        f32x4 d3 = a3 - b3;

        acc += (w2 * d0) * d0;
        acc += (w2 * d1) * d1;
        acc += (w2 * d2) * d2;
        acc += (w2 * d3) * d3;
    }

    // Parity-preserving XOR butterfly (even masks): reduces within parity class.
#pragma unroll
    for (int mask = 2; mask <= 32; mask <<= 1) {
        acc.x += __shfl_xor(acc.x, mask, 64);
        acc.y += __shfl_xor(acc.y, mask, 64);
        acc.z += __shfl_xor(acc.z, mask, 64);
        acc.w += __shfl_xor(acc.w, mask, 64);
    }
    // Lane 0 holds ch0-3 wave sum; lane 1 holds ch4-7 wave sum.

    __shared__ float sh[4][NY];               // 4 waves per 256-thread block
    const int wave = threadIdx.x >> 6;
    if (lane < 2) {
        sh[wave][lane * 4 + 0] = acc.x;
        sh[wave][lane * 4 + 1] = acc.y;
        sh[wave][lane * 4 + 2] = acc.z;
        sh[wave][lane * 4 + 3] = acc.w;
    }
    __syncthreads();

    // Per-block partials: every slot overwritten every call -> no memset, no atomics.
    if (threadIdx.x < NY) {
        const int ch = threadIdx.x;
        ws[blockIdx.x * NY + ch] = sh[0][ch] + sh[1][ch] + sh[2][ch] + sh[3][ch];
    }
}

// Stage 2: reduce GRID x 8 block partials, then sum sqrt(mean) over channels.
__global__ __launch_bounds__(256) void rmse_final_kernel(
    const float* __restrict__ ws, float* __restrict__ out)
{
    const int ch    = threadIdx.x & 7;        // channel
    const int slice = threadIdx.x >> 3;       // 32 slices over GRID blocks

    float s = 0.0f;
    for (int j = slice; j < GRID; j += 32)
        s += ws[j * NY + ch];

    // Same-channel lanes are stride-8 within the wave: masks 8,16,32.
    s += __shfl_xor(s, 8, 64);
    s += __shfl_xor(s, 16, 64);
    s += __shfl_xor(s, 32, 64);

    __shared__ float sh[4][NY];
    const int wave = threadIdx.x >> 6;
    const int lane = threadIdx.x & 63;
    if (lane < NY) sh[wave][lane] = s;
    __syncthreads();

    if (threadIdx.x == 0) {
        const float inv_n = 1.0f / (float)NGROUPS;  // mean over NT*NB per channel
        float total = 0.0f;
#pragma unroll
        for (int c = 0; c < NY; ++c) {
            float v = sh[0][c] + sh[1][c] + sh[2][c] + sh[3][c];
            total += sqrtf(v * inv_n);
        }
        out[0] = total;
    }
}

extern "C" void kernel_launch(void* const* d_in, const int* in_sizes, int n_in,
                              void* d_out, int out_size, void* d_ws, size_t ws_size,
                              hipStream_t stream) {
    const float* outp = (const float*)d_in[0];
    const float* tgtp = (const float*)d_in[1];
    float* ws  = (float*)d_ws;
    float* out = (float*)d_out;

    rmse_partial_kernel<<<GRID, BLOCK, 0, stream>>>(outp, tgtp, ws);
    rmse_final_kernel<<<1, 256, 0, stream>>>(ws, out);
}

// Round 10
// 218.835 us; speedup vs baseline: 1.3942x; 1.0202x over previous
//
#include <hip/hip_runtime.h>
#include <hip/hip_bf16.h>
#include <math.h>

#define NT 1200
#define NB 16384
#define NY 8
#define NGROUPS (NT * NB)                 // 19,660,800 channel-groups
#define NQ      (NT * NB * NY / 4)        // 39,321,600 float4 elements
#define GRID    1536                      // exactly 6 blocks/CU, 24 waves/CU (best measured)
#define BLOCK   256
#define NTHREADS (GRID * BLOCK)           // 393,216
#define CHUNK   4                         // 4 consecutive float4 = 64 B per array per iter
#define NITER   (NQ / (NTHREADS * CHUNK)) // 25, exact — no tail
#define W_LOW  0.2f
#define W_HIGH 1.75f

typedef float f32x4 __attribute__((ext_vector_type(4)));

// Stage 1: EXACT R6 memory schedule (best measured: 64 B contiguous per thread
// per array per iteration, 8 spatially-adjacent loads in flight, 24 waves/CU,
// 25 uniform iterations). Only the epilogue differs: per-block partials,
// no memset, no atomics.
__global__ __launch_bounds__(BLOCK) void rmse_partial_kernel(
    const float* __restrict__ outp, const float* __restrict__ tgtp,
    float* __restrict__ ws)
{
    const f32x4* __restrict__ o4 = reinterpret_cast<const f32x4*>(outp);
    const f32x4* __restrict__ t4 = reinterpret_cast<const f32x4*>(tgtp);

    const int c0 = blockIdx.x * BLOCK + threadIdx.x;

    f32x4 accA = {0.0f, 0.0f, 0.0f, 0.0f};   // channels 0-3
    f32x4 accB = {0.0f, 0.0f, 0.0f, 0.0f};   // channels 4-7

#pragma unroll 1
    for (int it = 0; it < NITER; ++it) {
        const int c   = c0 + it * NTHREADS;   // chunk index
        const int qb  = c << 2;               // first float4 of chunk
        const int t   = c >> 13;              // timestep (8192 chunks per t)
        const int mon = t % 12;
        const float w2 = (mon >= 6 && mon <= 9) ? (W_HIGH * W_HIGH)
                                                : (W_LOW * W_LOW);

        f32x4 a0 = o4[qb + 0];
        f32x4 a1 = o4[qb + 1];
        f32x4 a2 = o4[qb + 2];
        f32x4 a3 = o4[qb + 3];
        f32x4 b0 = t4[qb + 0];
        f32x4 b1 = t4[qb + 1];
        f32x4 b2 = t4[qb + 2];
        f32x4 b3 = t4[qb + 3];

        f32x4 d0 = a0 - b0;
        f32x4 d1 = a1 - b1;
        f32x4 d2 = a2 - b2;
        f32x4 d3 = a3 - b3;

        accA += (w2 * d0) * d0;
        accB += (w2 * d1) * d1;
        accA += (w2 * d2) * d2;
        accB += (w2 * d3) * d3;
    }

    // Full 64-lane XOR butterfly — every thread has the same channel mapping.
#pragma unroll
    for (int mask = 1; mask <= 32; mask <<= 1) {
        accA.x += __shfl_xor(accA.x, mask, 64);
        accA.y += __shfl_xor(accA.y, mask, 64);
        accA.z += __shfl_xor(accA.z, mask, 64);
        accA.w += __shfl_xor(accA.w, mask, 64);
        accB.x += __shfl_xor(accB.x, mask, 64);
        accB.y += __shfl_xor(accB.y, mask, 64);
        accB.z += __shfl_xor(accB.z, mask, 64);
        accB.w += __shfl_xor(accB.w, mask, 64);
    }

    __shared__ float sh[4][NY];               // 4 waves per 256-thread block
    const int wave = threadIdx.x >> 6;
    const int lane = threadIdx.x & 63;
    if (lane == 0) {
        sh[wave][0] = accA.x; sh[wave][1] = accA.y;
        sh[wave][2] = accA.z; sh[wave][3] = accA.w;
        sh[wave][4] = accB.x; sh[wave][5] = accB.y;
        sh[wave][6] = accB.z; sh[wave][7] = accB.w;
    }
    __syncthreads();

    // Per-block partials: every slot overwritten every call -> no memset, no atomics.
    if (threadIdx.x < NY) {
        const int ch = threadIdx.x;
        ws[blockIdx.x * NY + ch] = sh[0][ch] + sh[1][ch] + sh[2][ch] + sh[3][ch];
    }
}

// Stage 2: reduce GRID x 8 block partials, then sum sqrt(mean) over channels.
__global__ __launch_bounds__(256) void rmse_final_kernel(
    const float* __restrict__ ws, float* __restrict__ out)
{
    const int ch    = threadIdx.x & 7;        // channel
    const int slice = threadIdx.x >> 3;       // 32 slices over GRID blocks

    float s = 0.0f;
    for (int j = slice; j < GRID; j += 32)
        s += ws[j * NY + ch];

    // Same-channel lanes are stride-8 within the wave: masks 8,16,32.
    s += __shfl_xor(s, 8, 64);
    s += __shfl_xor(s, 16, 64);
    s += __shfl_xor(s, 32, 64);

    __shared__ float sh[4][NY];
    const int wave = threadIdx.x >> 6;
    const int lane = threadIdx.x & 63;
    if (lane < NY) sh[wave][lane] = s;
    __syncthreads();

    if (threadIdx.x == 0) {
        const float inv_n = 1.0f / (float)NGROUPS;  // mean over NT*NB per channel
        float total = 0.0f;
#pragma unroll
        for (int c = 0; c < NY; ++c) {
            float v = sh[0][c] + sh[1][c] + sh[2][c] + sh[3][c];
            total += sqrtf(v * inv_n);
        }
        out[0] = total;
    }
}

extern "C" void kernel_launch(void* const* d_in, const int* in_sizes, int n_in,
                              void* d_out, int out_size, void* d_ws, size_t ws_size,
                              hipStream_t stream) {
    const float* outp = (const float*)d_in[0];
    const float* tgtp = (const float*)d_in[1];
    float* ws  = (float*)d_ws;
    float* out = (float*)d_out;

    rmse_partial_kernel<<<GRID, BLOCK, 0, stream>>>(outp, tgtp, ws);
    rmse_final_kernel<<<1, 256, 0, stream>>>(ws, out);
}